// Round 5
// baseline (277.358 us; speedup 1.0000x reference)
//
#include <hip/hip_runtime.h>
#include <hip/hip_bf16.h>
#include <stdint.h>

#define AS_GLOBAL __attribute__((address_space(1)))
#define AS_LDS    __attribute__((address_space(3)))

typedef __attribute__((ext_vector_type(8))) short  bf16x8;
typedef __attribute__((ext_vector_type(4))) float  f32x4;
typedef __attribute__((ext_vector_type(8))) short  s16x8;

__device__ __forceinline__ void gload_lds16(const void* g, void* l) {
    __builtin_amdgcn_global_load_lds((AS_GLOBAL const void*)g, (AS_LDS void*)l, 16, 0, 0);
}

// Cast 8 fp32 -> 8 bf16 (one 16B store), pair index p into region (s,d).
__device__ __forceinline__ void cast_pair(const float* __restrict__ s,
                                          __hip_bfloat16* __restrict__ d, long p) {
    f32x4 a = ((const f32x4*)s)[p * 2];
    f32x4 b = ((const f32x4*)s)[p * 2 + 1];
    union { s16x8 p8; __hip_bfloat16 h[8]; } u;
    u.h[0] = __float2bfloat16(a.x); u.h[1] = __float2bfloat16(a.y);
    u.h[2] = __float2bfloat16(a.z); u.h[3] = __float2bfloat16(a.w);
    u.h[4] = __float2bfloat16(b.x); u.h[5] = __float2bfloat16(b.y);
    u.h[6] = __float2bfloat16(b.z); u.h[7] = __float2bfloat16(b.w);
    ((s16x8*)d)[p] = u.p8;
}

// x cast only: 1024x2048 fp32 -> bf16. 262144 pairs; 12 MB moved (~2.5us).
// R5: weights are no longer pre-cast at all (R4 showed the 180 MB cast stream
// costs 54us at a hard ~2.4 TB/s and nothing else overlaps it).
__global__ void cast_x_k(const float* __restrict__ x, __hip_bfloat16* __restrict__ xb) {
    long p = (long)blockIdx.x * 256 + threadIdx.x;
    cast_pair(x, xb, p);
}

// Split-K GEMM: P[z][M,N] = bf16( A[M,k0:k1] @ Bf[N,k0:k1]^T ), Bf is *fp32*.
//   A (bf16): staged via global_load_lds, verified 8-row-chunk XOR swizzle
//     (granule g of row r at slot g^(r&7)); 16 KB.
//   B (fp32): staged via global_load_lds DIRECTLY as fp32 (no pre-cast, no
//     VGPR round-trip -- unlike R2's failed reg-staging, the sync structure is
//     identical to the proven DMA path). 32 KB. Row = 256B = 8 granule-pairs
//     f (32B) x half h (16B); stored at slot h*8 + (f^(row&7)). Per-read bank
//     load is uniform (8 dwords/bank) => conflict-free by the same counting as
//     the verified bf16 scheme. Fragments: 2x ds_read_b128 + 8x cvt -> bf16x8;
//     cvt runs on VALU (8% busy) and co-schedules with MFMA (m114).
// Single-buffered, 48 KB LDS, launch_bounds(256,3) -> 3 blocks/CU.
// 128x128 tile, BK=64, 4 waves, 4x4 16x16x32 MFMA.
// TAG distinguishes layers in rocprof.
template <int TAG>
__global__ __launch_bounds__(256, 3)
void gemm_f(const __hip_bfloat16* __restrict__ A,
            const float* __restrict__ Bf,
            __hip_bfloat16* __restrict__ P,
            const int M, const int N, const int kchunk, const int S)
{
    __shared__ __hip_bfloat16 As[128 * 64];   // 16 KB
    __shared__ float          BsF[128 * 64];  // 32 KB

    const int tid = threadIdx.x;
    const int bn = blockIdx.x, bm = blockIdx.y, kz = blockIdx.z;

    const int lane = tid & 63;
    const int wave = tid >> 6;
    const int wm   = wave >> 1, wn = wave & 1;
    const int lm   = lane & 15, lq = lane >> 4;

    const int K  = kchunk * S;
    const int k0 = kz * kchunk;

    // A staging: 8-row chunks (1KB), lane covers row lane>>3, granule lane&7.
    const int rloA = lane >> 3;
    const int gswA = (((lane & 7) ^ rloA) << 3);   // bf16-element offset

    // B staging: 4-row chunks (1KB), lane covers row lane>>4, slot lane&15.
    // Slot s of row r holds global pair f=(s&7)^(r&7), half h=s>>3.
    const int rloB = lane >> 4;                    // 0..3
    const int hB   = (lane >> 3) & 1;              // s>>3
    const int s7B  = lane & 7;                     // s&7

    const __hip_bfloat16* Ag = A  + (size_t)(bm * 128) * K;
    const float*          Bg = Bf + (size_t)(bn * 128) * K;

    f32x4 acc[4][4];
    #pragma unroll
    for (int i = 0; i < 4; ++i)
        #pragma unroll
        for (int j = 0; j < 4; ++j)
            acc[i][j] = (f32x4){0.f, 0.f, 0.f, 0.f};

    for (int kt = k0; kt < k0 + kchunk; kt += 64) {
        __syncthreads();
        #pragma unroll
        for (int c = 0; c < 4; ++c) {
            const int chunk = wave * 4 + c;        // 0..15
            const int row   = chunk * 8 + rloA;    // 0..127
            gload_lds16(Ag + (size_t)row * K + kt + gswA, As + chunk * 512);
        }
        #pragma unroll
        for (int c = 0; c < 8; ++c) {
            const int q   = wave * 8 + c;          // 0..31
            const int row = q * 4 + rloB;          // 0..127
            const int f7  = s7B ^ (row & 7);       // stored pair index
            gload_lds16(Bg + (size_t)row * K + kt + f7 * 8 + hB * 4, BsF + q * 256);
        }
        __syncthreads();
        #pragma unroll
        for (int kk = 0; kk < 2; ++kk) {
            // A: granule G = kk*4+lq of row lives at slot G^(row&7); row&7==lm&7
            const int slA = (((kk * 4 + lq) ^ (lm & 7)) << 3);
            const int fB  = (kk * 4 + lq) ^ (lm & 7);
            bf16x8 af[4], bq[4];
            #pragma unroll
            for (int i = 0; i < 4; ++i)
                af[i] = *(const bf16x8*)(As + (wm * 64 + i * 16 + lm) * 64 + slA);
            #pragma unroll
            for (int j = 0; j < 4; ++j) {
                const float* bp = BsF + (wn * 64 + j * 16 + lm) * 64;
                f32x4 b0 = *(const f32x4*)(bp + fB * 4);        // half h=0
                f32x4 b1 = *(const f32x4*)(bp + 32 + fB * 4);   // half h=1
                union { s16x8 p8; __hip_bfloat16 h[8]; } u;
                u.h[0] = __float2bfloat16(b0.x); u.h[1] = __float2bfloat16(b0.y);
                u.h[2] = __float2bfloat16(b0.z); u.h[3] = __float2bfloat16(b0.w);
                u.h[4] = __float2bfloat16(b1.x); u.h[5] = __float2bfloat16(b1.y);
                u.h[6] = __float2bfloat16(b1.z); u.h[7] = __float2bfloat16(b1.w);
                bq[j] = (bf16x8)u.p8;
            }
            #pragma unroll
            for (int i = 0; i < 4; ++i)
                #pragma unroll
                for (int j = 0; j < 4; ++j)
                    acc[i][j] = __builtin_amdgcn_mfma_f32_16x16x32_bf16(af[i], bq[j], acc[i][j], 0, 0, 0);
        }
    }

    __hip_bfloat16* Pz = P + (size_t)kz * M * N;
    const int row0 = bm * 128 + wm * 64;
    const int colb = bn * 128 + wn * 64 + lm;
    #pragma unroll
    for (int j = 0; j < 4; ++j) {
        const int col = colb + j * 16;
        #pragma unroll
        for (int i = 0; i < 4; ++i)
            #pragma unroll
            for (int r = 0; r < 4; ++r) {
                const int row = row0 + i * 16 + lq * 4 + r;
                Pz[(size_t)row * N + col] = __float2bfloat16(acc[i][j][r]);
            }
    }
}

// T-collapse: za = sum_{u=1..T} w_u * relu(c_u*y + b2), where
// c_u = 1-beta1^u, w_u = (1-b2f)(1-b3f)*g_u, g_u = b2f*g_{u+1} + b3f^(T-u), g_T=1.
template <int TT>
__device__ __forceinline__ void tcollapse_coef(float be1, float be2, float be3,
                                               float* __restrict__ c, float* __restrict__ w) {
    float g[TT + 1];
    g[TT] = 1.f;
    float p3 = 1.f;
    #pragma unroll
    for (int u = TT - 1; u >= 1; --u) {
        p3 *= be3;
        g[u] = be2 * g[u + 1] + p3;
    }
    const float s = (1.f - be2) * (1.f - be3);
    float p1 = 1.f;
    #pragma unroll
    for (int u = 1; u <= TT; ++u) {
        p1 *= be1;
        c[u - 1] = 1.f - p1;
        w[u - 1] = s * g[u];
    }
}

// Sum S bf16 split-K partials (16B loads, fp32 accumulate) + epilogue. 8 elems/thread.
// MODE 0: bf16 out = relu(sum + bias)            (layer1 -> D1)
// MODE 1: bf16 out = T-collapse(y=sum, b2)       (layer2 -> Z)
// MODE 2: f32  out = sum + (1-beta3^T)*bias      (layer3 -> s3_T)
template <int MODE>
__global__ void reduce_k(const __hip_bfloat16* __restrict__ P, const int S,
                         void* __restrict__ outv, const long MN, const int N,
                         const float* __restrict__ bias,
                         const float* __restrict__ b_taus,
                         const int* __restrict__ Tp)
{
    long i8 = (long)blockIdx.x * 256 + threadIdx.x;   // 8-element group, exact cover
    long i  = i8 * 8;
    float a[8] = {0.f, 0.f, 0.f, 0.f, 0.f, 0.f, 0.f, 0.f};
    for (int s = 0; s < S; ++s) {
        union { s16x8 p8; __hip_bfloat16 h[8]; } u;
        u.p8 = *(const s16x8*)(P + (size_t)s * MN + i);
        #pragma unroll
        for (int c = 0; c < 8; ++c) a[c] += __bfloat162float(u.h[c]);
    }
    const int col = (int)(i % N);
    float bb[8];
    #pragma unroll
    for (int c = 0; c < 8; ++c) bb[c] = bias[col + c];

    if constexpr (MODE == 0) {
        union { s16x8 p8; __hip_bfloat16 h[8]; } u;
        #pragma unroll
        for (int c = 0; c < 8; ++c)
            u.h[c] = __float2bfloat16(fmaxf(a[c] + bb[c], 0.f));
        ((s16x8*)outv)[i8] = u.p8;
    } else if constexpr (MODE == 1) {
        const int   T   = *Tp;
        const float be1 = 1.f / (1.f + expf(-b_taus[0]));
        const float be2 = 1.f / (1.f + expf(-b_taus[1]));
        const float be3 = 1.f / (1.f + expf(-b_taus[2]));
        union { s16x8 p8; __hip_bfloat16 h[8]; } u;
        if (T == 10) {                     // fast path: fully unrolled, 10 independent terms
            float c10[10], w10[10];
            tcollapse_coef<10>(be1, be2, be3, c10, w10);
            #pragma unroll
            for (int c = 0; c < 8; ++c) {
                float za = 0.f;
                #pragma unroll
                for (int t = 0; t < 10; ++t)
                    za += w10[t] * fmaxf(fmaf(c10[t], a[c], bb[c]), 0.f);
                u.h[c] = __float2bfloat16(za);
            }
        } else {                           // generic fallback (original recurrence)
            #pragma unroll
            for (int c = 0; c < 8; ++c) {
                float p1 = 1.f, s2 = 0.f, za = 0.f;
                for (int t = 0; t < T; ++t) {
                    p1 *= be1;
                    const float d2 = fmaxf(fmaf(1.f - p1, a[c], bb[c]), 0.f);
                    s2 = be2 * s2 + (1.f - be2) * d2;
                    za = be3 * za + (1.f - be3) * s2;
                }
                u.h[c] = __float2bfloat16(za);
            }
        }
        ((s16x8*)outv)[i8] = u.p8;
    } else {
        const int   T   = *Tp;
        const float be3 = 1.f / (1.f + expf(-b_taus[2]));
        float g = 0.f;
        for (int t = 0; t < T; ++t) g = be3 * g + (1.f - be3);   // 1 - beta3^T
        f32x4 o0, o1;
        o0.x = a[0] + g * bb[0]; o0.y = a[1] + g * bb[1];
        o0.z = a[2] + g * bb[2]; o0.w = a[3] + g * bb[3];
        o1.x = a[4] + g * bb[4]; o1.y = a[5] + g * bb[5];
        o1.z = a[6] + g * bb[6]; o1.w = a[7] + g * bb[7];
        ((f32x4*)outv)[i8 * 2]     = o0;
        ((f32x4*)outv)[i8 * 2 + 1] = o1;
    }
}

extern "C" void kernel_launch(void* const* d_in, const int* in_sizes, int n_in,
                              void* d_out, int out_size, void* d_ws, size_t ws_size,
                              hipStream_t stream) {
    const float* x      = (const float*)d_in[0];
    const float* W1     = (const float*)d_in[1];
    const float* b1     = (const float*)d_in[2];
    const float* W2     = (const float*)d_in[3];
    const float* b2     = (const float*)d_in[4];
    const float* W3     = (const float*)d_in[5];
    const float* b3     = (const float*)d_in[6];
    const float* b_taus = (const float*)d_in[7];
    const int*   Tp     = (const int*)d_in[8];

    const int B = 1024, DIN = 2048, H1 = 4096, H2 = 4096, DOUT = 1024;
    const long MB = 1024 * 1024;

    // Arena (52 MB): xb 0 (4MB), D1b 4 (8MB), Sb 12 (8MB),
    // Pb 20 (32MB, shared by all split-K phases -- each dead before reuse).
    char* ws = (char*)d_ws;
    __hip_bfloat16* xb  = (__hip_bfloat16*)(ws + 0);
    __hip_bfloat16* D1b = (__hip_bfloat16*)(ws + 4 * MB);
    __hip_bfloat16* Sb  = (__hip_bfloat16*)(ws + 12 * MB);
    __hip_bfloat16* Pb  = (__hip_bfloat16*)(ws + 20 * MB);

    // x -> bf16 (12 MB moved; the only pre-cast left)
    cast_x_k<<<dim3(1024), dim3(256), 0, stream>>>(x, xb);

    // Layer 1: A=xb bf16, B=W1 fp32 direct. S=2 -> 512 blocks.
    gemm_f<1><<<dim3(H1 / 128, B / 128, 2), 256, 0, stream>>>(
        xb, W1, Pb, B, H1, DIN / 2, 2);
    reduce_k<0><<<dim3(2048), 256, 0, stream>>>(Pb, 2, (void*)D1b, (long)B * H1, H1, b1, nullptr, nullptr);

    // Layer 2: A=D1b bf16, B=W2 fp32 direct. S=4 -> 1024 blocks.
    gemm_f<2><<<dim3(H2 / 128, B / 128, 4), 256, 0, stream>>>(
        D1b, W2, Pb, B, H2, H1 / 4, 4);
    reduce_k<1><<<dim3(2048), 256, 0, stream>>>(Pb, 4, (void*)Sb, (long)B * H2, H2, b2, b_taus, Tp);

    // Layer 3: A=Sb bf16, B=W3 fp32 direct. S=8 -> 512 blocks.
    gemm_f<3><<<dim3(DOUT / 128, B / 128, 8), 256, 0, stream>>>(
        Sb, W3, Pb, B, DOUT, H2 / 8, 8);
    reduce_k<2><<<dim3(512), 256, 0, stream>>>(Pb, 8, d_out, (long)B * DOUT, DOUT, b3, b_taus, Tp);
}